// Round 9
// baseline (795.105 us; speedup 1.0000x reference)
//
#include <hip/hip_runtime.h>
#include <hip/hip_bf16.h>
#include <math.h>

// Problem constants
#define BB 8
#define LL 1024
#define DD 1024
#define FF 4096
#define NHH 8
#define HSS 128
#define SCALE 0.08838834764831845f  // 1/sqrt(128)
#define TRI(qi, kt) ((qi) * ((qi) + 1) / 2 + (kt))

typedef __bf16 bf16;
typedef __bf16 bf16x8 __attribute__((ext_vector_type(8)));
typedef float f32x4 __attribute__((ext_vector_type(4)));
typedef _Float16 f16;
typedef _Float16 f16x4 __attribute__((ext_vector_type(4)));

__device__ inline void async_copy16(const void* g, void* l) {
  __builtin_amdgcn_global_load_lds(
      (const __attribute__((address_space(1))) unsigned int*)g,
      (__attribute__((address_space(3))) unsigned int*)l, 16, 0, 0);
}

#define FENCE() asm volatile("" ::: "memory")
#define BARRIER() do { FENCE(); __builtin_amdgcn_s_barrier(); FENCE(); } while (0)
#define VMCNT0() asm volatile("s_waitcnt vmcnt(0)" ::: "memory")
#define VMCNT2() asm volatile("s_waitcnt vmcnt(2)" ::: "memory")
#define VMCNT4() asm volatile("s_waitcnt vmcnt(4)" ::: "memory")
#define VMCNT6() asm volatile("s_waitcnt vmcnt(6)" ::: "memory")

// ---------------------------------------------------------------------------
// prep: all weight transposes + Er pack in ONE launch.
// jobs by flat block id:
//   [0,3072)      W_qkv  [1024][3072] -> Wt  (bx=id%96,  by=id/96)
//   [3072,4096)   W_o    [1024][1024]        (bx=id%32,  by=id/32)
//   [4096,8192)   W_fc   [1024][4096]        (bx=id%128, by=id/128)
//   [8192,12288)  W_proj [4096][1024]        (bx=id%32,  by=id/32)
//   [12288,12352) pack_er group g = id-12288
// ---------------------------------------------------------------------------
__global__ __launch_bounds__(256)
void prep_kernel(const float* __restrict__ Wq, const float* __restrict__ Wo,
                 const float* __restrict__ Wf, const float* __restrict__ Wp,
                 const float* __restrict__ Er, bf16* __restrict__ Wtq,
                 bf16* __restrict__ Wto, bf16* __restrict__ Wtf,
                 bf16* __restrict__ Wtp, bf16* __restrict__ ErP) {
  __shared__ float tile[32][33];
  int id = blockIdx.x, tid = threadIdx.x;
  if (id >= 12288) {  // pack_er
    int g = id - 12288;
    int l15 = tid & 15, quad = (tid >> 4) & 3, st = tid >> 6;
    const float* src = Er + (size_t)(g * 16 + l15) * HSS + st * 32 + quad * 8;
    bf16* dst = ErP + (size_t)g * 2048 + tid * 8;
#pragma unroll
    for (int j = 0; j < 8; j++) dst[j] = (bf16)src[j];
    return;
  }
  const float* W;
  bf16* Wt;
  int K, N, bx, by;
  if (id < 3072)      { W = Wq; Wt = Wtq; K = 1024; N = 3072; bx = id % 96;  by = id / 96; }
  else if (id < 4096) { id -= 3072; W = Wo; Wt = Wto; K = 1024; N = 1024; bx = id % 32;  by = id / 32; }
  else if (id < 8192) { id -= 4096; W = Wf; Wt = Wtf; K = 1024; N = 4096; bx = id % 128; by = id / 128; }
  else                { id -= 8192; W = Wp; Wt = Wtp; K = 4096; N = 1024; bx = id % 32;  by = id / 32; }
  int n0 = bx * 32, k0 = by * 32;
  int tx = tid & 31, ty = tid >> 5;
#pragma unroll
  for (int i = 0; i < 32; i += 8)
    tile[ty + i][tx] = W[(size_t)(k0 + ty + i) * N + n0 + tx];
  __syncthreads();
#pragma unroll
  for (int i = 0; i < 32; i += 8)
    Wt[(size_t)(n0 + ty + i) * K + k0 + tx] = (bf16)tile[tx][ty + i];
}

// ---------------------------------------------------------------------------
// LayerNorm: x [8192][1024] fp32 -> out bf16
// ---------------------------------------------------------------------------
__global__ __launch_bounds__(256)
void ln_kernel(const float* __restrict__ x, const float* __restrict__ g,
               const float* __restrict__ bta, bf16* __restrict__ out) {
  int row = blockIdx.x;
  int tid = threadIdx.x;
  const float4 v = ((const float4*)(x + (size_t)row * DD))[tid];
  float s = v.x + v.y + v.z + v.w;
  float s2 = v.x * v.x + v.y * v.y + v.z * v.z + v.w * v.w;
#pragma unroll
  for (int o = 32; o > 0; o >>= 1) {
    s += __shfl_down(s, o);
    s2 += __shfl_down(s2, o);
  }
  __shared__ float a1[4], a2[4];
  int wave = tid >> 6;
  if ((tid & 63) == 0) { a1[wave] = s; a2[wave] = s2; }
  __syncthreads();
  s = a1[0] + a1[1] + a1[2] + a1[3];
  s2 = a2[0] + a2[1] + a2[2] + a2[3];
  float mu = s * (1.0f / DD);
  float rstd = rsqrtf(s2 * (1.0f / DD) - mu * mu + 1e-5f);
  float4 gv = ((const float4*)g)[tid];
  float4 bv = ((const float4*)bta)[tid];
  bf16* o4 = out + (size_t)row * DD + tid * 4;
  o4[0] = (bf16)((v.x - mu) * rstd * gv.x + bv.x);
  o4[1] = (bf16)((v.y - mu) * rstd * gv.y + bv.y);
  o4[2] = (bf16)((v.z - mu) * rstd * gv.z + bv.z);
  o4[3] = (bf16)((v.w - mu) * rstd * gv.w + bv.w);
}

// ---------------------------------------------------------------------------
// GEMM 256x256 8-phase A-lite (FC; measured best 113.8us, 3x confirmed).
// ---------------------------------------------------------------------------
template <int EPI>
__global__ __launch_bounds__(512)
void gemm256_kernel(const bf16* __restrict__ A, const bf16* __restrict__ Bt,
                    const float* __restrict__ bias, void* __restrict__ Cout,
                    int M, int N, int K) {
  __shared__ bf16 Als[2][256 * 64];
  __shared__ bf16 Bls[2][256 * 64];
  int tid = threadIdx.x;
  int wave = tid >> 6, lane = tid & 63;
  int l15 = lane & 15, quad = lane >> 4;
  int wmi = wave >> 2, wni = wave & 3;
  int m0 = blockIdx.y * 256, n0 = blockIdx.x * 256;

  int u0 = tid, u1 = tid + 512;
  int r0 = u0 >> 3, c0 = ((u0 & 7) ^ (r0 & 7)) << 3;
  int r1 = u1 >> 3, c1 = ((u1 & 7) ^ (r1 & 7)) << 3;
  const bf16* aB0 = A + (size_t)(m0 + r0) * K + c0;
  const bf16* aB1 = A + (size_t)(m0 + r1) * K + c1;
  const bf16* bB0 = Bt + (size_t)(n0 + r0) * K + c0;
  const bf16* bB1 = Bt + (size_t)(n0 + r1) * K + c1;
  int d0 = u0 * 8, d1 = u1 * 8;

  auto stageA = [&](int b, int h, int t) {
    size_t off = (size_t)h * 128 * K + (size_t)t * 64;
    async_copy16(aB0 + off, &Als[b][h * 8192 + d0]);
    async_copy16(aB1 + off, &Als[b][h * 8192 + d1]);
  };
  auto stageB = [&](int b, int h, int t) {
    size_t off = (size_t)h * 128 * K + (size_t)t * 64;
    async_copy16(bB0 + off, &Bls[b][h * 8192 + d0]);
    async_copy16(bB1 + off, &Bls[b][h * 8192 + d1]);
  };

  f32x4 acc[8][4] = {};
  bf16x8 af[2][4], bfr[2][2][2];  // bfr[qn][kk][nt]

  auto readA = [&](int b, int qm) {
#pragma unroll
    for (int kk = 0; kk < 2; kk++)
#pragma unroll
      for (int mt = 0; mt < 4; mt++) {
        int ra = qm * 128 + wmi * 64 + mt * 16 + l15;
        af[kk][mt] = *(const bf16x8*)&Als[b][ra * 64 + (((kk * 4 + quad) ^ (ra & 7)) << 3)];
      }
  };
  auto readB = [&](int b, int qn) {
#pragma unroll
    for (int kk = 0; kk < 2; kk++)
#pragma unroll
      for (int nt = 0; nt < 2; nt++) {
        int rb = qn * 128 + wni * 32 + nt * 16 + l15;
        bfr[qn][kk][nt] = *(const bf16x8*)&Bls[b][rb * 64 + (((kk * 4 + quad) ^ (rb & 7)) << 3)];
      }
  };
  auto mfma16 = [&](int qm, int qn) {
    __builtin_amdgcn_s_setprio(1);
#pragma unroll
    for (int kk = 0; kk < 2; kk++)
#pragma unroll
      for (int mt = 0; mt < 4; mt++)
#pragma unroll
        for (int nt = 0; nt < 2; nt++)
          acc[qm * 4 + mt][qn * 2 + nt] = __builtin_amdgcn_mfma_f32_16x16x32_bf16(
              af[kk][mt], bfr[qn][kk][nt], acc[qm * 4 + mt][qn * 2 + nt], 0, 0, 0);
    __builtin_amdgcn_s_setprio(0);
  };

  int nk = K >> 6;  // even
  stageA(0, 0, 0); stageB(0, 0, 0); stageB(0, 1, 0); stageA(0, 1, 0);
  stageA(1, 0, 1); stageB(1, 1, 1);
  VMCNT6();
  BARRIER();

  for (int t = 0; t < nk; t += 2) {
#pragma unroll
    for (int uu = 0; uu < 2; uu++) {
      const int tt = t + uu;
      const int cur = uu;
      // ph0: quadrant (0,0); read A0 + BOTH B quadrants
      readA(cur, 0); readB(cur, 0); readB(cur, 1);
      if (tt + 1 < nk) stageB(cur ^ 1, 0, tt + 1);
      BARRIER();
      mfma16(0, 0);
      BARRIER();
      // ph1: quadrant (0,1)
      if (tt + 1 < nk) stageA(cur ^ 1, 1, tt + 1);
      VMCNT6();
      BARRIER();
      mfma16(0, 1);
      BARRIER();
      // ph2: quadrant (1,1)
      readA(cur, 1);
      if (tt + 2 < nk) stageA(cur, 0, tt + 2);
      BARRIER();
      mfma16(1, 1);
      BARRIER();
      // ph3: quadrant (1,0)
      if (tt + 2 < nk) stageB(cur, 1, tt + 2);
      VMCNT6();
      BARRIER();
      mfma16(1, 0);
      BARRIER();
    }
  }

#pragma unroll
  for (int MT = 0; MT < 8; MT++) {
#pragma unroll
    for (int NT = 0; NT < 4; NT++) {
      int col = n0 + (NT >> 1) * 128 + wni * 32 + (NT & 1) * 16 + l15;
      float bv = bias[col];
#pragma unroll
      for (int r = 0; r < 4; r++) {
        int row = m0 + (MT >> 2) * 128 + wmi * 64 + (MT & 3) * 16 + quad * 4 + r;
        float v = acc[MT][NT][r] + bv;
        if (EPI == 1) v = 0.5f * v * (1.0f + erff(v * 0.7071067811865475f));
        ((bf16*)Cout)[(size_t)row * N + col] = (bf16)v;
      }
    }
  }
}

// ---------------------------------------------------------------------------
// GEMM 256x128 2-phase (QKV / attn-out / proj). R6-R8 verified.
// ---------------------------------------------------------------------------
template <int EPI>
__global__ __launch_bounds__(512)
void gemm256n_kernel(const bf16* __restrict__ A, const bf16* __restrict__ Bt,
                     const float* __restrict__ bias, const float* __restrict__ res,
                     void* __restrict__ Cout, int M, int N, int K) {
  __shared__ bf16 Als[2][256 * 64];
  __shared__ bf16 Bls[2][128 * 64];
  int tid = threadIdx.x;
  int wave = tid >> 6, lane = tid & 63;
  int l15 = lane & 15, quad = lane >> 4;
  int wmi = wave >> 2, wni = wave & 3;
  int m0 = blockIdx.y * 256, n0 = blockIdx.x * 128;

  int u0 = tid, u1 = tid + 512;
  int r0 = u0 >> 3, c0 = ((u0 & 7) ^ (r0 & 7)) << 3;
  int r1 = u1 >> 3, c1 = ((u1 & 7) ^ (r1 & 7)) << 3;
  const bf16* aB0 = A + (size_t)(m0 + r0) * K + c0;
  const bf16* aB1 = A + (size_t)(m0 + r1) * K + c1;
  const bf16* bB0 = Bt + (size_t)(n0 + r0) * K + c0;
  const bf16* bB1 = Bt + (size_t)(n0 + r1) * K + c1;
  int d0 = u0 * 8, d1 = u1 * 8;

  auto stageA = [&](int b, int h, int t) {
    size_t off = (size_t)h * 128 * K + (size_t)t * 64;
    async_copy16(aB0 + off, &Als[b][h * 8192 + d0]);
    async_copy16(aB1 + off, &Als[b][h * 8192 + d1]);
  };
  auto stageB = [&](int b, int t) {
    size_t off = (size_t)t * 64;
    async_copy16(bB0 + off, &Bls[b][d0]);
    async_copy16(bB1 + off, &Bls[b][d1]);
  };

  f32x4 acc[8][2] = {};
  bf16x8 af[2][4], bfr[2][2];

  auto readA = [&](int b, int qm) {
#pragma unroll
    for (int kk = 0; kk < 2; kk++)
#pragma unroll
      for (int mt = 0; mt < 4; mt++) {
        int ra = qm * 128 + wmi * 64 + mt * 16 + l15;
        af[kk][mt] = *(const bf16x8*)&Als[b][ra * 64 + (((kk * 4 + quad) ^ (ra & 7)) << 3)];
      }
  };
  auto readB = [&](int b) {
#pragma unroll
    for (int kk = 0; kk < 2; kk++)
#pragma unroll
      for (int nt = 0; nt < 2; nt++) {
        int rb = wni * 32 + nt * 16 + l15;
        bfr[kk][nt] = *(const bf16x8*)&Bls[b][rb * 64 + (((kk * 4 + quad) ^ (rb & 7)) << 3)];
      }
  };
  auto mfma16 = [&](int qm) {
    __builtin_amdgcn_s_setprio(1);
#pragma unroll
    for (int kk = 0; kk < 2; kk++)
#pragma unroll
      for (int mt = 0; mt < 4; mt++)
#pragma unroll
        for (int nt = 0; nt < 2; nt++)
          acc[qm * 4 + mt][nt] = __builtin_amdgcn_mfma_f32_16x16x32_bf16(
              af[kk][mt], bfr[kk][nt], acc[qm * 4 + mt][nt], 0, 0, 0);
    __builtin_amdgcn_s_setprio(0);
  };

  int nk = K >> 6;  // even
  stageB(0, 0); stageB(1, 1); stageA(0, 0, 0); stageA(0, 1, 0);
  VMCNT0();
  BARRIER();

  for (int t = 0; t < nk; t += 2) {
#pragma unroll
    for (int uu = 0; uu < 2; uu++) {
      const int tt = t + uu;
      const int cur = uu;
      // ph0
      readA(cur, 0); readB(cur);
      if (tt + 1 < nk) { stageA(cur ^ 1, 0, tt + 1); VMCNT4(); }
      else { VMCNT0(); }
      BARRIER();
      mfma16(0);
      BARRIER();
      // ph1
      readA(cur, 1);
      if (tt + 1 < nk) stageA(cur ^ 1, 1, tt + 1);
      if (tt + 2 < nk) { stageB(cur, tt + 2); VMCNT4(); }
      else { VMCNT2(); }
      BARRIER();
      mfma16(1);
      BARRIER();
    }
  }

#pragma unroll
  for (int MT = 0; MT < 8; MT++) {
#pragma unroll
    for (int NT = 0; NT < 2; NT++) {
      int col = n0 + wni * 32 + NT * 16 + l15;
      float bv = bias[col];
#pragma unroll
      for (int r = 0; r < 4; r++) {
        int row = m0 + (MT >> 2) * 128 + wmi * 64 + (MT & 3) * 16 + quad * 4 + r;
        float v = acc[MT][NT][r] + bv;
        if (EPI == 1) v = 0.5f * v * (1.0f + erff(v * 0.7071067811865475f));
        if (EPI == 2) {
          v += res[(size_t)row * N + col];
          ((float*)Cout)[(size_t)row * N + col] = v;
        } else {
          ((bf16*)Cout)[(size_t)row * N + col] = (bf16)v;
        }
      }
    }
  }
}

// ---------------------------------------------------------------------------
// pack_v: per (b,h,kt) V transposed into [d][chunk^swizzle], 16B chunks.
// ---------------------------------------------------------------------------
__global__ __launch_bounds__(256)
void pack_v_kernel(const bf16* __restrict__ qkv, bf16* __restrict__ Vpack) {
  __shared__ bf16 Vst[64][132];
  int kt = blockIdx.x, h = blockIdx.y, b = blockIdx.z;
  int tid = threadIdx.x;
  const size_t rs = 3 * DD;
  const bf16* vb = qkv + (size_t)b * LL * rs + (size_t)(kt * 64) * rs + 2 * DD + h * HSS;
  bf16* vp = Vpack + ((size_t)(b * NHH + h) * 16 + kt) * (128 * 64);
#pragma unroll
  for (int i = 0; i < 4; i++) {
    int u = i * 256 + tid;
    int kk = u >> 4, c = u & 15;
    *(bf16x8*)&Vst[kk][c * 8] = *(const bf16x8*)(vb + (size_t)kk * rs + c * 8);
  }
  __syncthreads();
#pragma unroll
  for (int i = 0; i < 4; i++) {
    int u = i * 256 + tid;
    int d = u >> 3, c = u & 7;
    bf16x8 t;
#pragma unroll
    for (int j = 0; j < 8; j++) t[j] = Vst[c * 8 + j][d];
    *(bf16x8*)(vp + d * 64 + ((c ^ (d & 7))) * 8) = t;
  }
}

// ---------------------------------------------------------------------------
// Flash attention v10: relband FUSED (v2 of the R3 attempt, defects fixed).
// Per k-tile: Srel computed in-register via R = Q@ErP^T (fragment-major ErP:
// each ef fragment is ONE contiguous 1KB wave load, L2-resident — fixes R3's
// scattered loads), then R3's verified skew gather via __shfl, f32 combine.
// Load order per tile: sync -> ef loads (ALL, before DMA: counted vmcnt
// retire leaves the 8 prefetch DMAs in flight) -> prefetch DMA -> rr MFMA ->
// QK^T -> softmax (T13 defer-max) -> PV. K staged direct from qkv
// (pre-swizzled global, R8-verified). Deletes relband kernel + 66MB band
// write + 60MB read + one launch.
// ---------------------------------------------------------------------------
__global__ __launch_bounds__(256)
void flash_kernel(const bf16* __restrict__ qkv, const bf16* __restrict__ Vpack,
                  const bf16* __restrict__ ErP, bf16* __restrict__ y) {
  __shared__ bf16 Kls[2][64 * 128];
  __shared__ bf16 Vls[2][128 * 64];
  __shared__ bf16 Pls[4][16][72];

  int tid = threadIdx.x, wave = tid >> 6, lane = tid & 63;
  int l15 = lane & 15, quad = lane >> 4;
  int h = blockIdx.y, b = blockIdx.z;

  const size_t rs = 3 * DD;
  const bf16* qbase = qkv + (size_t)b * LL * rs + h * HSS;
  const bf16* kb = qbase + DD;  // K head base
  const bf16* vp = Vpack + (size_t)(b * NHH + h) * 16 * (128 * 64);

  // per-thread pre-swizzled K source offsets (tile-invariant part)
  size_t koff[4];
  int ldso[4];
#pragma unroll
  for (int i = 0; i < 4; i++) {
    int off = (wave * 4 + i) * 512 + lane * 8;
    int u = off >> 3;
    int kk = u >> 4, c = u & 15;
    koff[i] = (size_t)kk * rs + (size_t)(((c ^ kk) & 15) * 8);
    ldso[i] = off;
  }

  int buf = 0;
#pragma unroll 1
  for (int ph = 0; ph < 2; ph++) {
    int qb = ph ? 15 - blockIdx.x : blockIdx.x;
    int qw0 = qb * 64 + wave * 16;
    int nkt = qb + 1;

    bf16x8 qf[4];
#pragma unroll
    for (int st = 0; st < 4; st++)
      qf[st] = *(const bf16x8*)(qbase + (size_t)(qw0 + l15) * rs + st * 32 + quad * 8);

    // prologue DMA: tile 0
#pragma unroll
    for (int i = 0; i < 4; i++) {
      async_copy16(kb + koff[i], &Kls[buf][ldso[i]]);
      async_copy16(vp + ldso[i], &Vls[buf][ldso[i]]);
    }

    f32x4 o[8] = {};
    float mrow[4] = {-INFINITY, -INFINITY, -INFINITY, -INFINITY};
    float lrow[4] = {0.f, 0.f, 0.f, 0.f};

#pragma unroll 1
    for (int kt = 0; kt < nkt; kt++) {
      int k0 = kt * 64;
      int kmax_off = qw0 + 15 - k0;  // wave-uniform
      int m_base = 1008 - qw0 + k0;  // >= 0, multiple of 16
      int gb = m_base >> 4;
      int ntR = (kmax_off >> 4) + 1;
      if (ntR > 4) ntR = 4;
      __syncthreads();  // tile kt's K/V resident; prev readers done

      // (1) ef loads FIRST (before prefetch DMA): compiler's counted vmcnt
      // for rr-use leaves the 8 younger DMA loads in flight (in-order retire)
      bf16x8 ef[5][4];
#pragma unroll
      for (int n = 0; n < 5; n++) {
        if (n <= ntR) {
          int g = gb + n;
          if (g > 63) g = 63;  // g>=64: all elems m>1023 -> masked downstream
          const bf16* ep = ErP + (size_t)g * 2048 + lane * 8;
#pragma unroll
          for (int st = 0; st < 4; st++)
            ef[n][st] = *(const bf16x8*)(ep + st * 512);
        }
      }

      // (2) prefetch DMA: tile kt+1 into alternate buffer
      if (kt + 1 < nkt) {
        const bf16* ks = kb + (size_t)(kt + 1) * 64 * rs;
        const bf16* vs = vp + (size_t)(kt + 1) * (128 * 64);
#pragma unroll
        for (int i = 0; i < 4; i++) {
          async_copy16(ks + koff[i], &Kls[buf ^ 1][ldso[i]]);
          async_copy16(vs + ldso[i], &Vls[buf ^ 1][ldso[i]]);
        }
      }

      // (3) R = Q @ Er^T: rr[n][rg] = R[qw0+quad*4+rg][m_base+n*16+l15]
      f32x4 rr[5] = {};
      __builtin_amdgcn_s_setprio(1);
#pragma unroll
      for (int n = 0; n < 5; n++) {
        if (n <= ntR) {
#pragma unroll
          for (int st = 0; st < 4; st++)
            rr[n] = __builtin_amdgcn_mfma_f32_16x16x32_bf16(qf[st], ef[n][st], rr[n], 0, 0, 0);
        }
      }
      __builtin_amdgcn_s_setprio(0);

      // (4) S = Q K^T
      f32x4 sa[4] = {};
      __builtin_amdgcn_s_setprio(1);
#pragma unroll
      for (int nt = 0; nt < 4; nt++) {
        if (nt * 16 <= kmax_off) {
          int kk = nt * 16 + l15;
#pragma unroll
          for (int st = 0; st < 4; st++) {
            bf16x8 kf = *(const bf16x8*)&Kls[buf][kk * 128 + (((st * 4 + quad) ^ l15) & 15) * 8];
            sa[nt] = __builtin_amdgcn_mfma_f32_16x16x32_bf16(qf[st], kf, sa[nt], 0, 0, 0);
          }
        }
      }
      __builtin_amdgcn_s_setprio(0);

      // (5) skew gather + combine + mask + row max (R3-verified math)
      float pmx[4] = {-INFINITY, -INFINITY, -INFINITY, -INFINITY};
#pragma unroll
      for (int rg = 0; rg < 4; rg++) {
        int qloc = quad * 4 + rg;
        int qg = qw0 + qloc;
        int tt = 15 - qloc + l15;           // 0..30
        int src = (lane & 48) | (tt & 15);  // same quad-row, rotated col
        float shv[5];
#pragma unroll
        for (int n = 0; n < 5; n++)
          shv[n] = (n <= ntR) ? __shfl(rr[n][rg], src) : 0.f;
#pragma unroll
        for (int nt = 0; nt < 4; nt++) {
          if (nt * 16 <= kmax_off) {
            int kg = k0 + nt * 16 + l15;
            float srel = (tt & 16) ? shv[nt + 1] : shv[nt];
            float v = (sa[nt][rg] + srel) * SCALE;
            v = (kg <= qg) ? v : -INFINITY;
            sa[nt][rg] = v;
            pmx[rg] = fmaxf(pmx[rg], v);
          } else {
            sa[nt][rg] = -INFINITY;
          }
        }
      }

      // (6) online softmax with defer-max (T13)
      float vmx[4];
      bool need = false;
#pragma unroll
      for (int rg = 0; rg < 4; rg++) {
        float v = pmx[rg];
        v = fmaxf(v, __shfl_xor(v, 1));
        v = fmaxf(v, __shfl_xor(v, 2));
        v = fmaxf(v, __shfl_xor(v, 4));
        v = fmaxf(v, __shfl_xor(v, 8));
        vmx[rg] = v;
        need = need || (v - mrow[rg] > 8.0f);
      }
      if (__any(need)) {
#pragma unroll
        for (int rg = 0; rg < 4; rg++) {
          float mnew = fmaxf(mrow[rg], vmx[rg]);
          float alpha = __expf(mrow[rg] - mnew);
          mrow[rg] = mnew;
          lrow[rg] *= alpha;
#pragma unroll
          for (int nt = 0; nt < 8; nt++) o[nt][rg] *= alpha;
        }
      }

      float ls[4] = {0.f, 0.f, 0.f, 0.f};
#pragma unroll
      for (int nt = 0; nt < 4; nt++)
#pragma unroll
        for (int rg = 0; rg < 4; rg++) {
          float p = __expf(sa[nt][rg] - mrow[rg]);
          ls[rg] += p;
          Pls[wave][quad * 4 + rg][nt * 16 + l15] = (bf16)p;
        }
#pragma unroll
      for (int rg = 0; rg < 4; rg++) {
        float v = ls[rg];
        v += __shfl_xor(v, 1);
        v += __shfl_xor(v, 2);
        v += __shfl_xor(v, 4);
        v += __shfl_xor(v, 8);
        lrow[rg] += v;
      }

      // (7) O += P @ V
      bf16x8 pf[2];
#pragma unroll
      for (int s2 = 0; s2 < 2; s2++)
        pf[s2] = *(const bf16x8*)&Pls[wave][l15][s2 * 32 + quad * 8];
      __builtin_amdgcn_s_setprio(1);
#pragma unroll
      for (int nt = 0; nt < 8; nt++) {
        int d = nt * 16 + l15;
#pragma unroll
        for (int s2 = 0; s2 < 2; s2++) {
          if (s2 * 32 <= kmax_off) {
            bf16x8 vf = *(const bf16x8*)&Vls[buf][d * 64 + (((s2 * 4 + quad) ^ (l15 & 7)) & 7) * 8];
            o[nt] = __builtin_amdgcn_mfma_f32_16x16x32_bf16(pf[s2], vf, o[nt], 0, 0, 0);
          }
        }
      }
      __builtin_amdgcn_s_setprio(0);
      buf ^= 1;
    }

#pragma unroll
    for (int rg = 0; rg < 4; rg++) {
      float inv = 1.0f / lrow[rg];
      int qg = qw0 + quad * 4 + rg;
      bf16* yr = y + ((size_t)b * LL + qg) * DD + h * HSS;
#pragma unroll
      for (int nt = 0; nt < 8; nt++) yr[nt * 16 + l15] = (bf16)(o[nt][rg] * inv);
    }
  }
}

// ---------------------------------------------------------------------------
extern "C" void kernel_launch(void* const* d_in, const int* in_sizes, int n_in,
                              void* d_out, int out_size, void* d_ws, size_t ws_size,
                              hipStream_t stream) {
  const float* x = (const float*)d_in[0];
  const float* W_qkv = (const float*)d_in[1];
  const float* b_qkv = (const float*)d_in[2];
  const float* W_o = (const float*)d_in[3];
  const float* b_o = (const float*)d_in[4];
  const float* Er = (const float*)d_in[5];
  const float* ln1_g = (const float*)d_in[6];
  const float* ln1_b = (const float*)d_in[7];
  const float* ln2_g = (const float*)d_in[8];
  const float* ln2_b = (const float*)d_in[9];
  const float* W_fc = (const float*)d_in[10];
  const float* b_fc = (const float*)d_in[11];
  const float* W_proj = (const float*)d_in[12];
  const float* b_proj = (const float*)d_in[13];
  float* out = (float*)d_out;

  char* p = (char*)d_ws;
  auto alloc = [&](size_t bytes) {
    char* r = p;
    p += (bytes + 255) & ~(size_t)255;
    return r;
  };
  bf16* Wt_qkv = (bf16*)alloc((size_t)3072 * 1024 * 2);
  bf16* Wt_o   = (bf16*)alloc((size_t)1024 * 1024 * 2);
  bf16* Wt_fc  = (bf16*)alloc((size_t)4096 * 1024 * 2);
  bf16* Wt_pr  = (bf16*)alloc((size_t)1024 * 4096 * 2);
  bf16* ErP    = (bf16*)alloc((size_t)1024 * 128 * 2);
  bf16* xn     = (bf16*)alloc((size_t)8192 * 1024 * 2);
  bf16* qkvb   = (bf16*)alloc((size_t)8192 * 3072 * 2);  // + yb = hb region
  bf16* yb     = (bf16*)alloc((size_t)8192 * 1024 * 2);  // must follow qkvb
  bf16* Vpack  = (bf16*)alloc((size_t)64 * 16 * 128 * 64 * 2);
  float* x2    = (float*)alloc((size_t)8192 * 1024 * 4);  // 32 MB
  bf16* hb     = qkvb;          // spans qkvb+yb (66MB >= 64MB needed)

  // weight prep (single launch)
  prep_kernel<<<12352, 256, 0, stream>>>(W_qkv, W_o, W_fc, W_proj, Er,
                                         Wt_qkv, Wt_o, Wt_fc, Wt_pr, ErP);

  // block
  ln_kernel<<<8192, 256, 0, stream>>>(x, ln1_g, ln1_b, xn);
  gemm256n_kernel<0><<<dim3(24, 32), 512, 0, stream>>>(xn, Wt_qkv, b_qkv, nullptr, qkvb, 8192, 3072, 1024);
  pack_v_kernel<<<dim3(16, 8, 8), 256, 0, stream>>>(qkvb, Vpack);
  flash_kernel<<<dim3(8, 8, 8), 256, 0, stream>>>(qkvb, Vpack, ErP, yb);
  gemm256n_kernel<2><<<dim3(8, 32), 512, 0, stream>>>(yb, Wt_o, b_o, x, x2, 8192, 1024, 1024);
  ln_kernel<<<8192, 256, 0, stream>>>(x2, ln2_g, ln2_b, xn);
  gemm256_kernel<1><<<dim3(16, 32), 512, 0, stream>>>(xn, Wt_fc, b_fc, hb, 8192, 4096, 1024);
  gemm256n_kernel<2><<<dim3(8, 32), 512, 0, stream>>>(hb, Wt_pr, b_proj, x2, out, 8192, 1024, 4096);
}

// Round 11
// 713.706 us; speedup vs baseline: 1.1141x; 1.1141x over previous
//
#include <hip/hip_runtime.h>
#include <hip/hip_bf16.h>
#include <math.h>

// Problem constants
#define BB 8
#define LL 1024
#define DD 1024
#define FF 4096
#define NHH 8
#define HSS 128
#define SCALE 0.08838834764831845f  // 1/sqrt(128)
#define TRI(qi, kt) ((qi) * ((qi) + 1) / 2 + (kt))

typedef __bf16 bf16;
typedef __bf16 bf16x8 __attribute__((ext_vector_type(8)));
typedef float f32x4 __attribute__((ext_vector_type(4)));
typedef _Float16 f16;
typedef _Float16 f16x4 __attribute__((ext_vector_type(4)));

__device__ inline void async_copy16(const void* g, void* l) {
  __builtin_amdgcn_global_load_lds(
      (const __attribute__((address_space(1))) unsigned int*)g,
      (__attribute__((address_space(3))) unsigned int*)l, 16, 0, 0);
}

#define FENCE() asm volatile("" ::: "memory")
#define BARRIER() do { FENCE(); __builtin_amdgcn_s_barrier(); FENCE(); } while (0)
#define VMCNT0() asm volatile("s_waitcnt vmcnt(0)" ::: "memory")
#define VMCNT2() asm volatile("s_waitcnt vmcnt(2)" ::: "memory")
#define VMCNT4() asm volatile("s_waitcnt vmcnt(4)" ::: "memory")
#define VMCNT6() asm volatile("s_waitcnt vmcnt(6)" ::: "memory")

// ---------------------------------------------------------------------------
// prep: all weight transposes + Er pack in ONE launch.
// jobs by flat block id:
//   [0,3072)      W_qkv  [1024][3072] -> Wt  (bx=id%96,  by=id/96)
//   [3072,4096)   W_o    [1024][1024]        (bx=id%32,  by=id/32)
//   [4096,8192)   W_fc   [1024][4096]        (bx=id%128, by=id/128)
//   [8192,12288)  W_proj [4096][1024]        (bx=id%32,  by=id/32)
//   [12288,12352) pack_er group g = id-12288
// ---------------------------------------------------------------------------
__global__ __launch_bounds__(256)
void prep_kernel(const float* __restrict__ Wq, const float* __restrict__ Wo,
                 const float* __restrict__ Wf, const float* __restrict__ Wp,
                 const float* __restrict__ Er, bf16* __restrict__ Wtq,
                 bf16* __restrict__ Wto, bf16* __restrict__ Wtf,
                 bf16* __restrict__ Wtp, bf16* __restrict__ ErP) {
  __shared__ float tile[32][33];
  int id = blockIdx.x, tid = threadIdx.x;
  if (id >= 12288) {  // pack_er
    int g = id - 12288;
    int l15 = tid & 15, quad = (tid >> 4) & 3, st = tid >> 6;
    const float* src = Er + (size_t)(g * 16 + l15) * HSS + st * 32 + quad * 8;
    bf16* dst = ErP + (size_t)g * 2048 + tid * 8;
#pragma unroll
    for (int j = 0; j < 8; j++) dst[j] = (bf16)src[j];
    return;
  }
  const float* W;
  bf16* Wt;
  int K, N, bx, by;
  if (id < 3072)      { W = Wq; Wt = Wtq; K = 1024; N = 3072; bx = id % 96;  by = id / 96; }
  else if (id < 4096) { id -= 3072; W = Wo; Wt = Wto; K = 1024; N = 1024; bx = id % 32;  by = id / 32; }
  else if (id < 8192) { id -= 4096; W = Wf; Wt = Wtf; K = 1024; N = 4096; bx = id % 128; by = id / 128; }
  else                { id -= 8192; W = Wp; Wt = Wtp; K = 4096; N = 1024; bx = id % 32;  by = id / 32; }
  int n0 = bx * 32, k0 = by * 32;
  int tx = tid & 31, ty = tid >> 5;
#pragma unroll
  for (int i = 0; i < 32; i += 8)
    tile[ty + i][tx] = W[(size_t)(k0 + ty + i) * N + n0 + tx];
  __syncthreads();
#pragma unroll
  for (int i = 0; i < 32; i += 8)
    Wt[(size_t)(n0 + ty + i) * K + k0 + tx] = (bf16)tile[tx][ty + i];
}

// ---------------------------------------------------------------------------
// LayerNorm: x [8192][1024] fp32 -> out bf16
// ---------------------------------------------------------------------------
__global__ __launch_bounds__(256)
void ln_kernel(const float* __restrict__ x, const float* __restrict__ g,
               const float* __restrict__ bta, bf16* __restrict__ out) {
  int row = blockIdx.x;
  int tid = threadIdx.x;
  const float4 v = ((const float4*)(x + (size_t)row * DD))[tid];
  float s = v.x + v.y + v.z + v.w;
  float s2 = v.x * v.x + v.y * v.y + v.z * v.z + v.w * v.w;
#pragma unroll
  for (int o = 32; o > 0; o >>= 1) {
    s += __shfl_down(s, o);
    s2 += __shfl_down(s2, o);
  }
  __shared__ float a1[4], a2[4];
  int wave = tid >> 6;
  if ((tid & 63) == 0) { a1[wave] = s; a2[wave] = s2; }
  __syncthreads();
  s = a1[0] + a1[1] + a1[2] + a1[3];
  s2 = a2[0] + a2[1] + a2[2] + a2[3];
  float mu = s * (1.0f / DD);
  float rstd = rsqrtf(s2 * (1.0f / DD) - mu * mu + 1e-5f);
  float4 gv = ((const float4*)g)[tid];
  float4 bv = ((const float4*)bta)[tid];
  bf16* o4 = out + (size_t)row * DD + tid * 4;
  o4[0] = (bf16)((v.x - mu) * rstd * gv.x + bv.x);
  o4[1] = (bf16)((v.y - mu) * rstd * gv.y + bv.y);
  o4[2] = (bf16)((v.z - mu) * rstd * gv.z + bv.z);
  o4[3] = (bf16)((v.w - mu) * rstd * gv.w + bv.w);
}

// ---------------------------------------------------------------------------
// GEMM 256x256 8-phase A-lite (FC; measured best 113.8us, 3x confirmed).
// ---------------------------------------------------------------------------
template <int EPI>
__global__ __launch_bounds__(512)
void gemm256_kernel(const bf16* __restrict__ A, const bf16* __restrict__ Bt,
                    const float* __restrict__ bias, void* __restrict__ Cout,
                    int M, int N, int K) {
  __shared__ bf16 Als[2][256 * 64];
  __shared__ bf16 Bls[2][256 * 64];
  int tid = threadIdx.x;
  int wave = tid >> 6, lane = tid & 63;
  int l15 = lane & 15, quad = lane >> 4;
  int wmi = wave >> 2, wni = wave & 3;
  int m0 = blockIdx.y * 256, n0 = blockIdx.x * 256;

  int u0 = tid, u1 = tid + 512;
  int r0 = u0 >> 3, c0 = ((u0 & 7) ^ (r0 & 7)) << 3;
  int r1 = u1 >> 3, c1 = ((u1 & 7) ^ (r1 & 7)) << 3;
  const bf16* aB0 = A + (size_t)(m0 + r0) * K + c0;
  const bf16* aB1 = A + (size_t)(m0 + r1) * K + c1;
  const bf16* bB0 = Bt + (size_t)(n0 + r0) * K + c0;
  const bf16* bB1 = Bt + (size_t)(n0 + r1) * K + c1;
  int d0 = u0 * 8, d1 = u1 * 8;

  auto stageA = [&](int b, int h, int t) {
    size_t off = (size_t)h * 128 * K + (size_t)t * 64;
    async_copy16(aB0 + off, &Als[b][h * 8192 + d0]);
    async_copy16(aB1 + off, &Als[b][h * 8192 + d1]);
  };
  auto stageB = [&](int b, int h, int t) {
    size_t off = (size_t)h * 128 * K + (size_t)t * 64;
    async_copy16(bB0 + off, &Bls[b][h * 8192 + d0]);
    async_copy16(bB1 + off, &Bls[b][h * 8192 + d1]);
  };

  f32x4 acc[8][4] = {};
  bf16x8 af[2][4], bfr[2][2][2];  // bfr[qn][kk][nt]

  auto readA = [&](int b, int qm) {
#pragma unroll
    for (int kk = 0; kk < 2; kk++)
#pragma unroll
      for (int mt = 0; mt < 4; mt++) {
        int ra = qm * 128 + wmi * 64 + mt * 16 + l15;
        af[kk][mt] = *(const bf16x8*)&Als[b][ra * 64 + (((kk * 4 + quad) ^ (ra & 7)) << 3)];
      }
  };
  auto readB = [&](int b, int qn) {
#pragma unroll
    for (int kk = 0; kk < 2; kk++)
#pragma unroll
      for (int nt = 0; nt < 2; nt++) {
        int rb = qn * 128 + wni * 32 + nt * 16 + l15;
        bfr[qn][kk][nt] = *(const bf16x8*)&Bls[b][rb * 64 + (((kk * 4 + quad) ^ (rb & 7)) << 3)];
      }
  };
  auto mfma16 = [&](int qm, int qn) {
    __builtin_amdgcn_s_setprio(1);
#pragma unroll
    for (int kk = 0; kk < 2; kk++)
#pragma unroll
      for (int mt = 0; mt < 4; mt++)
#pragma unroll
        for (int nt = 0; nt < 2; nt++)
          acc[qm * 4 + mt][qn * 2 + nt] = __builtin_amdgcn_mfma_f32_16x16x32_bf16(
              af[kk][mt], bfr[qn][kk][nt], acc[qm * 4 + mt][qn * 2 + nt], 0, 0, 0);
    __builtin_amdgcn_s_setprio(0);
  };

  int nk = K >> 6;  // even
  stageA(0, 0, 0); stageB(0, 0, 0); stageB(0, 1, 0); stageA(0, 1, 0);
  stageA(1, 0, 1); stageB(1, 1, 1);
  VMCNT6();
  BARRIER();

  for (int t = 0; t < nk; t += 2) {
#pragma unroll
    for (int uu = 0; uu < 2; uu++) {
      const int tt = t + uu;
      const int cur = uu;
      // ph0: quadrant (0,0); read A0 + BOTH B quadrants
      readA(cur, 0); readB(cur, 0); readB(cur, 1);
      if (tt + 1 < nk) stageB(cur ^ 1, 0, tt + 1);
      BARRIER();
      mfma16(0, 0);
      BARRIER();
      // ph1: quadrant (0,1)
      if (tt + 1 < nk) stageA(cur ^ 1, 1, tt + 1);
      VMCNT6();
      BARRIER();
      mfma16(0, 1);
      BARRIER();
      // ph2: quadrant (1,1)
      readA(cur, 1);
      if (tt + 2 < nk) stageA(cur, 0, tt + 2);
      BARRIER();
      mfma16(1, 1);
      BARRIER();
      // ph3: quadrant (1,0)
      if (tt + 2 < nk) stageB(cur, 1, tt + 2);
      VMCNT6();
      BARRIER();
      mfma16(1, 0);
      BARRIER();
    }
  }

#pragma unroll
  for (int MT = 0; MT < 8; MT++) {
#pragma unroll
    for (int NT = 0; NT < 4; NT++) {
      int col = n0 + (NT >> 1) * 128 + wni * 32 + (NT & 1) * 16 + l15;
      float bv = bias[col];
#pragma unroll
      for (int r = 0; r < 4; r++) {
        int row = m0 + (MT >> 2) * 128 + wmi * 64 + (MT & 3) * 16 + quad * 4 + r;
        float v = acc[MT][NT][r] + bv;
        if (EPI == 1) v = 0.5f * v * (1.0f + erff(v * 0.7071067811865475f));
        ((bf16*)Cout)[(size_t)row * N + col] = (bf16)v;
      }
    }
  }
}

// ---------------------------------------------------------------------------
// GEMM 256x128 2-phase (QKV / attn-out / proj). R6-R8 verified.
// ---------------------------------------------------------------------------
template <int EPI>
__global__ __launch_bounds__(512)
void gemm256n_kernel(const bf16* __restrict__ A, const bf16* __restrict__ Bt,
                     const float* __restrict__ bias, const float* __restrict__ res,
                     void* __restrict__ Cout, int M, int N, int K) {
  __shared__ bf16 Als[2][256 * 64];
  __shared__ bf16 Bls[2][128 * 64];
  int tid = threadIdx.x;
  int wave = tid >> 6, lane = tid & 63;
  int l15 = lane & 15, quad = lane >> 4;
  int wmi = wave >> 2, wni = wave & 3;
  int m0 = blockIdx.y * 256, n0 = blockIdx.x * 128;

  int u0 = tid, u1 = tid + 512;
  int r0 = u0 >> 3, c0 = ((u0 & 7) ^ (r0 & 7)) << 3;
  int r1 = u1 >> 3, c1 = ((u1 & 7) ^ (r1 & 7)) << 3;
  const bf16* aB0 = A + (size_t)(m0 + r0) * K + c0;
  const bf16* aB1 = A + (size_t)(m0 + r1) * K + c1;
  const bf16* bB0 = Bt + (size_t)(n0 + r0) * K + c0;
  const bf16* bB1 = Bt + (size_t)(n0 + r1) * K + c1;
  int d0 = u0 * 8, d1 = u1 * 8;

  auto stageA = [&](int b, int h, int t) {
    size_t off = (size_t)h * 128 * K + (size_t)t * 64;
    async_copy16(aB0 + off, &Als[b][h * 8192 + d0]);
    async_copy16(aB1 + off, &Als[b][h * 8192 + d1]);
  };
  auto stageB = [&](int b, int t) {
    size_t off = (size_t)t * 64;
    async_copy16(bB0 + off, &Bls[b][d0]);
    async_copy16(bB1 + off, &Bls[b][d1]);
  };

  f32x4 acc[8][2] = {};
  bf16x8 af[2][4], bfr[2][2];

  auto readA = [&](int b, int qm) {
#pragma unroll
    for (int kk = 0; kk < 2; kk++)
#pragma unroll
      for (int mt = 0; mt < 4; mt++) {
        int ra = qm * 128 + wmi * 64 + mt * 16 + l15;
        af[kk][mt] = *(const bf16x8*)&Als[b][ra * 64 + (((kk * 4 + quad) ^ (ra & 7)) << 3)];
      }
  };
  auto readB = [&](int b) {
#pragma unroll
    for (int kk = 0; kk < 2; kk++)
#pragma unroll
      for (int nt = 0; nt < 2; nt++) {
        int rb = wni * 32 + nt * 16 + l15;
        bfr[kk][nt] = *(const bf16x8*)&Bls[b][rb * 64 + (((kk * 4 + quad) ^ (rb & 7)) << 3)];
      }
  };
  auto mfma16 = [&](int qm) {
    __builtin_amdgcn_s_setprio(1);
#pragma unroll
    for (int kk = 0; kk < 2; kk++)
#pragma unroll
      for (int mt = 0; mt < 4; mt++)
#pragma unroll
        for (int nt = 0; nt < 2; nt++)
          acc[qm * 4 + mt][nt] = __builtin_amdgcn_mfma_f32_16x16x32_bf16(
              af[kk][mt], bfr[kk][nt], acc[qm * 4 + mt][nt], 0, 0, 0);
    __builtin_amdgcn_s_setprio(0);
  };

  int nk = K >> 6;  // even
  stageB(0, 0); stageB(1, 1); stageA(0, 0, 0); stageA(0, 1, 0);
  VMCNT0();
  BARRIER();

  for (int t = 0; t < nk; t += 2) {
#pragma unroll
    for (int uu = 0; uu < 2; uu++) {
      const int tt = t + uu;
      const int cur = uu;
      // ph0
      readA(cur, 0); readB(cur);
      if (tt + 1 < nk) { stageA(cur ^ 1, 0, tt + 1); VMCNT4(); }
      else { VMCNT0(); }
      BARRIER();
      mfma16(0);
      BARRIER();
      // ph1
      readA(cur, 1);
      if (tt + 1 < nk) stageA(cur ^ 1, 1, tt + 1);
      if (tt + 2 < nk) { stageB(cur, tt + 2); VMCNT4(); }
      else { VMCNT2(); }
      BARRIER();
      mfma16(1);
      BARRIER();
    }
  }

#pragma unroll
  for (int MT = 0; MT < 8; MT++) {
#pragma unroll
    for (int NT = 0; NT < 2; NT++) {
      int col = n0 + wni * 32 + NT * 16 + l15;
      float bv = bias[col];
#pragma unroll
      for (int r = 0; r < 4; r++) {
        int row = m0 + (MT >> 2) * 128 + wmi * 64 + (MT & 3) * 16 + quad * 4 + r;
        float v = acc[MT][NT][r] + bv;
        if (EPI == 1) v = 0.5f * v * (1.0f + erff(v * 0.7071067811865475f));
        if (EPI == 2) {
          v += res[(size_t)row * N + col];
          ((float*)Cout)[(size_t)row * N + col] = v;
        } else {
          ((bf16*)Cout)[(size_t)row * N + col] = (bf16)v;
        }
      }
    }
  }
}

// ---------------------------------------------------------------------------
// pack_v: per (b,h,kt) V transposed into [d][chunk^swizzle], 16B chunks.
// ---------------------------------------------------------------------------
__global__ __launch_bounds__(256)
void pack_v_kernel(const bf16* __restrict__ qkv, bf16* __restrict__ Vpack) {
  __shared__ bf16 Vst[64][132];
  int kt = blockIdx.x, h = blockIdx.y, b = blockIdx.z;
  int tid = threadIdx.x;
  const size_t rs = 3 * DD;
  const bf16* vb = qkv + (size_t)b * LL * rs + (size_t)(kt * 64) * rs + 2 * DD + h * HSS;
  bf16* vp = Vpack + ((size_t)(b * NHH + h) * 16 + kt) * (128 * 64);
#pragma unroll
  for (int i = 0; i < 4; i++) {
    int u = i * 256 + tid;
    int kk = u >> 4, c = u & 15;
    *(bf16x8*)&Vst[kk][c * 8] = *(const bf16x8*)(vb + (size_t)kk * rs + c * 8);
  }
  __syncthreads();
#pragma unroll
  for (int i = 0; i < 4; i++) {
    int u = i * 256 + tid;
    int d = u >> 3, c = u & 7;
    bf16x8 t;
#pragma unroll
    for (int j = 0; j < 8; j++) t[j] = Vst[c * 8 + j][d];
    *(bf16x8*)(vp + d * 64 + ((c ^ (d & 7))) * 8) = t;
  }
}

// ---------------------------------------------------------------------------
// relband v4 + setprio (R6-R8 proven, ~45us, occupancy 36%).
// ---------------------------------------------------------------------------
__global__ __launch_bounds__(256)
void relband_kernel(const bf16* __restrict__ qkv, const bf16* __restrict__ ErP,
                    f16* __restrict__ band) {
  int tid = threadIdx.x, wave = tid >> 6, lane = tid & 63;
  int l15 = lane & 15, quad = lane >> 4;
  int h = blockIdx.y, b = blockIdx.z;
  const size_t rs = 3 * DD;
  const bf16* qbase = qkv + (size_t)b * LL * rs + h * HSS;
  f16* bbase = band + (size_t)(b * NHH + h) * (136 * 4096);

#pragma unroll 1
  for (int ph = 0; ph < 2; ph++) {
    int qb = ph ? 15 - blockIdx.x : blockIdx.x;
    int qw0 = qb * 64 + wave * 16;

    bf16x8 qf[4];
#pragma unroll
    for (int st = 0; st < 4; st++)
      qf[st] = *(const bf16x8*)(qbase + (size_t)(qw0 + l15) * rs + st * 32 + quad * 8);

#pragma unroll 1
    for (int kt = 0; kt <= qb; kt++) {
      int k0 = kt * 64;
      int kmax_off = qw0 + 15 - k0;
      int m_base = 1008 - qw0 + k0;
      int gb = m_base >> 4;
      int ntR = (kmax_off >> 4) + 1;
      if (ntR > 4) ntR = 4;

      f32x4 rr[5] = {};
      __builtin_amdgcn_s_setprio(1);
#pragma unroll
      for (int n = 0; n < 5; n++) {
        if (n <= ntR) {
          int g = gb + n;
          if (g > 63) g = 63;
          const bf16* ep = ErP + (size_t)g * 2048 + lane * 8;
#pragma unroll
          for (int st = 0; st < 4; st++) {
            bf16x8 ef = *(const bf16x8*)(ep + st * 512);
            rr[n] = __builtin_amdgcn_mfma_f32_16x16x32_bf16(qf[st], ef, rr[n], 0, 0, 0);
          }
        }
      }
      __builtin_amdgcn_s_setprio(0);

      f16x4 sf[4];
#pragma unroll
      for (int rg = 0; rg < 4; rg++) {
        int qloc = quad * 4 + rg;
        int tt = 15 - qloc + l15;
        int src = (lane & 48) | (tt & 15);
        float shv[5];
#pragma unroll
        for (int n = 0; n < 5; n++)
          shv[n] = (n <= ntR) ? __shfl(rr[n][rg], src) : 0.f;
#pragma unroll
        for (int nt = 0; nt < 4; nt++)
          sf[nt][rg] = (f16)((tt & 16) ? shv[nt + 1] : shv[nt]);
      }
      f16* tb = bbase + (size_t)TRI(qb, kt) * 4096;
#pragma unroll
      for (int nt = 0; nt < 4; nt++)
        if (nt * 16 <= kmax_off)
          *(f16x4*)(tb + (wave * 4 + nt) * 256 + l15 * 16 + quad * 4) = sf[nt];
    }
  }
}

// ---------------------------------------------------------------------------
// Flash attention v11: SINGLE-buffered K/V, ~42KB LDS -> 2-3 blocks/CU.
// R9 lesson: flash at 1 block/CU (79KB dbuf) is latency-bound with zero TLP;
// m97/m114 philosophy: at >=2 blocks/CU cross-block wave overlap hides the
// staging drain better than an explicit prefetch pipeline at 1 block/CU.
// Two __syncthreads per k-tile (stage-then-compute). K staged direct from
// qkv via pre-swizzled global addresses (R8-verified); V from Vpack; band
// from relband. setprio + T13 defer-max kept (R7/R8 verified).
// ---------------------------------------------------------------------------
__global__ __launch_bounds__(256)
void flash_kernel(const bf16* __restrict__ qkv, const bf16* __restrict__ Vpack,
                  const f16* __restrict__ band, bf16* __restrict__ y) {
  __shared__ bf16 Kls[64 * 128];   // 16 KB
  __shared__ bf16 Vls[128 * 64];   // 16 KB
  __shared__ bf16 Pls[4][16][72];  // 9 KB

  int tid = threadIdx.x, wave = tid >> 6, lane = tid & 63;
  int l15 = lane & 15, quad = lane >> 4;
  int h = blockIdx.y, b = blockIdx.z;

  const size_t rs = 3 * DD;
  const bf16* qbase = qkv + (size_t)b * LL * rs + h * HSS;
  const bf16* kb = qbase + DD;  // K head base
  const bf16* vp = Vpack + (size_t)(b * NHH + h) * 16 * (128 * 64);
  const f16* bnd = band + (size_t)(b * NHH + h) * (136 * 4096);

  // per-thread pre-swizzled K source offsets (tile-invariant part)
  size_t koff[4];
  int ldso[4];
#pragma unroll
  for (int i = 0; i < 4; i++) {
    int off = (wave * 4 + i) * 512 + lane * 8;
    int u = off >> 3;
    int kk = u >> 4, c = u & 15;
    koff[i] = (size_t)kk * rs + (size_t)(((c ^ kk) & 15) * 8);
    ldso[i] = off;
  }

#pragma unroll 1
  for (int ph = 0; ph < 2; ph++) {
    int qb = ph ? 15 - blockIdx.x : blockIdx.x;
    int qw0 = qb * 64 + wave * 16;
    int nkt = qb + 1;

    bf16x8 qf[4];
#pragma unroll
    for (int st = 0; st < 4; st++)
      qf[st] = *(const bf16x8*)(qbase + (size_t)(qw0 + l15) * rs + st * 32 + quad * 8);

    f32x4 o[8] = {};
    float mrow[4] = {-INFINITY, -INFINITY, -INFINITY, -INFINITY};
    float lrow[4] = {0.f, 0.f, 0.f, 0.f};

#pragma unroll 1
    for (int kt = 0; kt < nkt; kt++) {
      int k0 = kt * 64;
      int kmax_off = qw0 + 15 - k0;  // wave-uniform
      __syncthreads();  // previous tile's (and phase's) readers done

      // band fragment loads (VGPR; retire with the barrier drain below)
      const f16* tb = bnd + (size_t)TRI(qb, kt) * 4096;
      f16x4 srl[4] = {};
#pragma unroll
      for (int nt = 0; nt < 4; nt++)
        if (nt * 16 <= kmax_off)
          srl[nt] = *(const f16x4*)(tb + (wave * 4 + nt) * 256 + l15 * 16 + quad * 4);

      // stage THIS tile's K/V
      {
        const bf16* ks = kb + (size_t)kt * 64 * rs;
        const bf16* vs = vp + (size_t)kt * (128 * 64);
#pragma unroll
        for (int i = 0; i < 4; i++) {
          async_copy16(ks + koff[i], &Kls[ldso[i]]);
          async_copy16(vs + ldso[i], &Vls[ldso[i]]);
        }
      }
      __syncthreads();  // drain: K/V resident, srl ready

      // S = Q K^T
      f32x4 sa[4] = {};
      __builtin_amdgcn_s_setprio(1);
#pragma unroll
      for (int nt = 0; nt < 4; nt++) {
        if (nt * 16 <= kmax_off) {
          int kk = nt * 16 + l15;
#pragma unroll
          for (int st = 0; st < 4; st++) {
            bf16x8 kf = *(const bf16x8*)&Kls[kk * 128 + (((st * 4 + quad) ^ l15) & 15) * 8];
            sa[nt] = __builtin_amdgcn_mfma_f32_16x16x32_bf16(qf[st], kf, sa[nt], 0, 0, 0);
          }
        }
      }
      __builtin_amdgcn_s_setprio(0);

      // combine + mask + row max
      float pmx[4] = {-INFINITY, -INFINITY, -INFINITY, -INFINITY};
#pragma unroll
      for (int nt = 0; nt < 4; nt++) {
        if (nt * 16 <= kmax_off) {
          int kg = k0 + nt * 16 + l15;
#pragma unroll
          for (int rg = 0; rg < 4; rg++) {
            int qg = qw0 + quad * 4 + rg;
            float v = (sa[nt][rg] + (float)srl[nt][rg]) * SCALE;
            v = (kg <= qg) ? v : -INFINITY;
            sa[nt][rg] = v;
            pmx[rg] = fmaxf(pmx[rg], v);
          }
        } else {
#pragma unroll
          for (int rg = 0; rg < 4; rg++) sa[nt][rg] = -INFINITY;
        }
      }

      // online softmax with defer-max (T13)
      float vmx[4];
      bool need = false;
#pragma unroll
      for (int rg = 0; rg < 4; rg++) {
        float v = pmx[rg];
        v = fmaxf(v, __shfl_xor(v, 1));
        v = fmaxf(v, __shfl_xor(v, 2));
        v = fmaxf(v, __shfl_xor(v, 4));
        v = fmaxf(v, __shfl_xor(v, 8));
        vmx[rg] = v;
        need = need || (v - mrow[rg] > 8.0f);
      }
      if (__any(need)) {
#pragma unroll
        for (int rg = 0; rg < 4; rg++) {
          float mnew = fmaxf(mrow[rg], vmx[rg]);
          float alpha = __expf(mrow[rg] - mnew);
          mrow[rg] = mnew;
          lrow[rg] *= alpha;
#pragma unroll
          for (int nt = 0; nt < 8; nt++) o[nt][rg] *= alpha;
        }
      }

      float ls[4] = {0.f, 0.f, 0.f, 0.f};
#pragma unroll
      for (int nt = 0; nt < 4; nt++)
#pragma unroll
        for (int rg = 0; rg < 4; rg++) {
          float p = __expf(sa[nt][rg] - mrow[rg]);
          ls[rg] += p;
          Pls[wave][quad * 4 + rg][nt * 16 + l15] = (bf16)p;
        }
#pragma unroll
      for (int rg = 0; rg < 4; rg++) {
        float v = ls[rg];
        v += __shfl_xor(v, 1);
        v += __shfl_xor(v, 2);
        v += __shfl_xor(v, 4);
        v += __shfl_xor(v, 8);
        lrow[rg] += v;
      }
      // Pls is per-wave: same-wave DS ordering suffices, no barrier

      // O += P @ V
      bf16x8 pf[2];
#pragma unroll
      for (int s2 = 0; s2 < 2; s2++)
        pf[s2] = *(const bf16x8*)&Pls[wave][l15][s2 * 32 + quad * 8];
      __builtin_amdgcn_s_setprio(1);
#pragma unroll
      for (int nt = 0; nt < 8; nt++) {
        int d = nt * 16 + l15;
#pragma unroll
        for (int s2 = 0; s2 < 2; s2++) {
          if (s2 * 32 <= kmax_off) {
            bf16x8 vf = *(const bf16x8*)&Vls[d * 64 + (((s2 * 4 + quad) ^ (l15 & 7)) & 7) * 8];
            o[nt] = __builtin_amdgcn_mfma_f32_16x16x32_bf16(pf[s2], vf, o[nt], 0, 0, 0);
          }
        }
      }
      __builtin_amdgcn_s_setprio(0);
    }

    // finalize phase: O / l -> y[b, q, h*128 + d] bf16
#pragma unroll
    for (int rg = 0; rg < 4; rg++) {
      float inv = 1.0f / lrow[rg];
      int qg = qw0 + quad * 4 + rg;
      bf16* yr = y + ((size_t)b * LL + qg) * DD + h * HSS;
#pragma unroll
      for (int nt = 0; nt < 8; nt++) yr[nt * 16 + l15] = (bf16)(o[nt][rg] * inv);
    }
  }
}

// ---------------------------------------------------------------------------
extern "C" void kernel_launch(void* const* d_in, const int* in_sizes, int n_in,
                              void* d_out, int out_size, void* d_ws, size_t ws_size,
                              hipStream_t stream) {
  const float* x = (const float*)d_in[0];
  const float* W_qkv = (const float*)d_in[1];
  const float* b_qkv = (const float*)d_in[2];
  const float* W_o = (const float*)d_in[3];
  const float* b_o = (const float*)d_in[4];
  const float* Er = (const float*)d_in[5];
  const float* ln1_g = (const float*)d_in[6];
  const float* ln1_b = (const float*)d_in[7];
  const float* ln2_g = (const float*)d_in[8];
  const float* ln2_b = (const float*)d_in[9];
  const float* W_fc = (const float*)d_in[10];
  const float* b_fc = (const float*)d_in[11];
  const float* W_proj = (const float*)d_in[12];
  const float* b_proj = (const float*)d_in[13];
  float* out = (float*)d_out;

  char* p = (char*)d_ws;
  auto alloc = [&](size_t bytes) {
    char* r = p;
    p += (bytes + 255) & ~(size_t)255;
    return r;
  };
  bf16* Wt_qkv = (bf16*)alloc((size_t)3072 * 1024 * 2);
  bf16* Wt_o   = (bf16*)alloc((size_t)1024 * 1024 * 2);
  bf16* Wt_fc  = (bf16*)alloc((size_t)4096 * 1024 * 2);
  bf16* Wt_pr  = (bf16*)alloc((size_t)1024 * 4096 * 2);
  bf16* ErP    = (bf16*)alloc((size_t)1024 * 128 * 2);
  bf16* xn     = (bf16*)alloc((size_t)8192 * 1024 * 2);
  bf16* qkvb   = (bf16*)alloc((size_t)8192 * 3072 * 2);  // + yb = hb region
  bf16* yb     = (bf16*)alloc((size_t)8192 * 1024 * 2);  // must follow qkvb
  bf16* Vpack  = (bf16*)alloc((size_t)64 * 16 * 128 * 64 * 2);
  f16*  band   = (f16*)alloc((size_t)64 * 136 * 4096 * 2);  // 71.3 MB
  float* x2    = (float*)band;  // alias: band dead before x2 is written
  bf16* hb     = qkvb;          // spans qkvb+yb (66MB >= 64MB needed)

  // weight prep (single launch)
  prep_kernel<<<12352, 256, 0, stream>>>(W_qkv, W_o, W_fc, W_proj, Er,
                                         Wt_qkv, Wt_o, Wt_fc, Wt_pr, ErP);

  // block
  ln_kernel<<<8192, 256, 0, stream>>>(x, ln1_g, ln1_b, xn);
  gemm256n_kernel<0><<<dim3(24, 32), 512, 0, stream>>>(xn, Wt_qkv, b_qkv, nullptr, qkvb, 8192, 3072, 1024);
  pack_v_kernel<<<dim3(16, 8, 8), 256, 0, stream>>>(qkvb, Vpack);
  relband_kernel<<<dim3(8, 8, 8), 256, 0, stream>>>(qkvb, ErP, band);
  flash_kernel<<<dim3(8, 8, 8), 256, 0, stream>>>(qkvb, Vpack, band, yb);
  gemm256n_kernel<2><<<dim3(8, 32), 512, 0, stream>>>(yb, Wt_o, b_o, x, x2, 8192, 1024, 1024);
  ln_kernel<<<8192, 256, 0, stream>>>(x2, ln2_g, ln2_b, xn);
  gemm256_kernel<1><<<dim3(16, 32), 512, 0, stream>>>(xn, Wt_fc, b_fc, hb, 8192, 4096, 1024);
  gemm256n_kernel<2><<<dim3(8, 32), 512, 0, stream>>>(hb, Wt_pr, b_proj, x2, out, 8192, 1024, 4096);
}

// Round 12
// 600.475 us; speedup vs baseline: 1.3241x; 1.1886x over previous
//
#include <hip/hip_runtime.h>
#include <hip/hip_bf16.h>
#include <math.h>

// Problem constants
#define BB 8
#define LL 1024
#define DD 1024
#define FF 4096
#define NHH 8
#define HSS 128
#define SCALE 0.08838834764831845f  // 1/sqrt(128)
#define TRI(qi, kt) ((qi) * ((qi) + 1) / 2 + (kt))

typedef __bf16 bf16;
typedef __bf16 bf16x8 __attribute__((ext_vector_type(8)));
typedef float f32x4 __attribute__((ext_vector_type(4)));
typedef _Float16 f16;
typedef _Float16 f16x4 __attribute__((ext_vector_type(4)));

__device__ inline void async_copy16(const void* g, void* l) {
  __builtin_amdgcn_global_load_lds(
      (const __attribute__((address_space(1))) unsigned int*)g,
      (__attribute__((address_space(3))) unsigned int*)l, 16, 0, 0);
}

#define FENCE() asm volatile("" ::: "memory")
#define BARRIER() do { FENCE(); __builtin_amdgcn_s_barrier(); FENCE(); } while (0)
#define VMCNT0() asm volatile("s_waitcnt vmcnt(0)" ::: "memory")
#define VMCNT2() asm volatile("s_waitcnt vmcnt(2)" ::: "memory")
#define VMCNT4() asm volatile("s_waitcnt vmcnt(4)" ::: "memory")
#define VMCNT6() asm volatile("s_waitcnt vmcnt(6)" ::: "memory")

// ---------------------------------------------------------------------------
// prep: all weight transposes + Er pack in ONE launch.
// jobs by flat block id:
//   [0,3072)      W_qkv  [1024][3072] -> Wt  (bx=id%96,  by=id/96)
//   [3072,4096)   W_o    [1024][1024]        (bx=id%32,  by=id/32)
//   [4096,8192)   W_fc   [1024][4096]        (bx=id%128, by=id/128)
//   [8192,12288)  W_proj [4096][1024]        (bx=id%32,  by=id/32)
//   [12288,12352) pack_er group g = id-12288
// ---------------------------------------------------------------------------
__global__ __launch_bounds__(256)
void prep_kernel(const float* __restrict__ Wq, const float* __restrict__ Wo,
                 const float* __restrict__ Wf, const float* __restrict__ Wp,
                 const float* __restrict__ Er, bf16* __restrict__ Wtq,
                 bf16* __restrict__ Wto, bf16* __restrict__ Wtf,
                 bf16* __restrict__ Wtp, bf16* __restrict__ ErP) {
  __shared__ float tile[32][33];
  int id = blockIdx.x, tid = threadIdx.x;
  if (id >= 12288) {  // pack_er
    int g = id - 12288;
    int l15 = tid & 15, quad = (tid >> 4) & 3, st = tid >> 6;
    const float* src = Er + (size_t)(g * 16 + l15) * HSS + st * 32 + quad * 8;
    bf16* dst = ErP + (size_t)g * 2048 + tid * 8;
#pragma unroll
    for (int j = 0; j < 8; j++) dst[j] = (bf16)src[j];
    return;
  }
  const float* W;
  bf16* Wt;
  int K, N, bx, by;
  if (id < 3072)      { W = Wq; Wt = Wtq; K = 1024; N = 3072; bx = id % 96;  by = id / 96; }
  else if (id < 4096) { id -= 3072; W = Wo; Wt = Wto; K = 1024; N = 1024; bx = id % 32;  by = id / 32; }
  else if (id < 8192) { id -= 4096; W = Wf; Wt = Wtf; K = 1024; N = 4096; bx = id % 128; by = id / 128; }
  else                { id -= 8192; W = Wp; Wt = Wtp; K = 4096; N = 1024; bx = id % 32;  by = id / 32; }
  int n0 = bx * 32, k0 = by * 32;
  int tx = tid & 31, ty = tid >> 5;
#pragma unroll
  for (int i = 0; i < 32; i += 8)
    tile[ty + i][tx] = W[(size_t)(k0 + ty + i) * N + n0 + tx];
  __syncthreads();
#pragma unroll
  for (int i = 0; i < 32; i += 8)
    Wt[(size_t)(n0 + ty + i) * K + k0 + tx] = (bf16)tile[tx][ty + i];
}

// ---------------------------------------------------------------------------
// LayerNorm: x [8192][1024] fp32 -> out bf16
// ---------------------------------------------------------------------------
__global__ __launch_bounds__(256)
void ln_kernel(const float* __restrict__ x, const float* __restrict__ g,
               const float* __restrict__ bta, bf16* __restrict__ out) {
  int row = blockIdx.x;
  int tid = threadIdx.x;
  const float4 v = ((const float4*)(x + (size_t)row * DD))[tid];
  float s = v.x + v.y + v.z + v.w;
  float s2 = v.x * v.x + v.y * v.y + v.z * v.z + v.w * v.w;
#pragma unroll
  for (int o = 32; o > 0; o >>= 1) {
    s += __shfl_down(s, o);
    s2 += __shfl_down(s2, o);
  }
  __shared__ float a1[4], a2[4];
  int wave = tid >> 6;
  if ((tid & 63) == 0) { a1[wave] = s; a2[wave] = s2; }
  __syncthreads();
  s = a1[0] + a1[1] + a1[2] + a1[3];
  s2 = a2[0] + a2[1] + a2[2] + a2[3];
  float mu = s * (1.0f / DD);
  float rstd = rsqrtf(s2 * (1.0f / DD) - mu * mu + 1e-5f);
  float4 gv = ((const float4*)g)[tid];
  float4 bv = ((const float4*)bta)[tid];
  bf16* o4 = out + (size_t)row * DD + tid * 4;
  o4[0] = (bf16)((v.x - mu) * rstd * gv.x + bv.x);
  o4[1] = (bf16)((v.y - mu) * rstd * gv.y + bv.y);
  o4[2] = (bf16)((v.z - mu) * rstd * gv.z + bv.z);
  o4[3] = (bf16)((v.w - mu) * rstd * gv.w + bv.w);
}

// ---------------------------------------------------------------------------
// GEMM 256x256 8-phase (FC). Read-balanced rev: ds_reads 16/8/8/0 per phase
// (A-lite's 24/0/8/0 front-loaded a long lgkm chain into ph0). B-fragments
// register-held as before; B1's read moved to ph1 — its covering wait is
// the PREVIOUS iteration's ph3 vmcnt(6), which precedes ph1. Stage schedule,
// waits and barriers byte-identical to the R5-R8-verified ledger.
// ---------------------------------------------------------------------------
template <int EPI>
__global__ __launch_bounds__(512)
void gemm256_kernel(const bf16* __restrict__ A, const bf16* __restrict__ Bt,
                    const float* __restrict__ bias, void* __restrict__ Cout,
                    int M, int N, int K) {
  __shared__ bf16 Als[2][256 * 64];
  __shared__ bf16 Bls[2][256 * 64];
  int tid = threadIdx.x;
  int wave = tid >> 6, lane = tid & 63;
  int l15 = lane & 15, quad = lane >> 4;
  int wmi = wave >> 2, wni = wave & 3;
  int m0 = blockIdx.y * 256, n0 = blockIdx.x * 256;

  int u0 = tid, u1 = tid + 512;
  int r0 = u0 >> 3, c0 = ((u0 & 7) ^ (r0 & 7)) << 3;
  int r1 = u1 >> 3, c1 = ((u1 & 7) ^ (r1 & 7)) << 3;
  const bf16* aB0 = A + (size_t)(m0 + r0) * K + c0;
  const bf16* aB1 = A + (size_t)(m0 + r1) * K + c1;
  const bf16* bB0 = Bt + (size_t)(n0 + r0) * K + c0;
  const bf16* bB1 = Bt + (size_t)(n0 + r1) * K + c1;
  int d0 = u0 * 8, d1 = u1 * 8;

  auto stageA = [&](int b, int h, int t) {
    size_t off = (size_t)h * 128 * K + (size_t)t * 64;
    async_copy16(aB0 + off, &Als[b][h * 8192 + d0]);
    async_copy16(aB1 + off, &Als[b][h * 8192 + d1]);
  };
  auto stageB = [&](int b, int h, int t) {
    size_t off = (size_t)h * 128 * K + (size_t)t * 64;
    async_copy16(bB0 + off, &Bls[b][h * 8192 + d0]);
    async_copy16(bB1 + off, &Bls[b][h * 8192 + d1]);
  };

  f32x4 acc[8][4] = {};
  bf16x8 af[2][4], bfr[2][2][2];  // bfr[qn][kk][nt]

  auto readA = [&](int b, int qm) {
#pragma unroll
    for (int kk = 0; kk < 2; kk++)
#pragma unroll
      for (int mt = 0; mt < 4; mt++) {
        int ra = qm * 128 + wmi * 64 + mt * 16 + l15;
        af[kk][mt] = *(const bf16x8*)&Als[b][ra * 64 + (((kk * 4 + quad) ^ (ra & 7)) << 3)];
      }
  };
  auto readB = [&](int b, int qn) {
#pragma unroll
    for (int kk = 0; kk < 2; kk++)
#pragma unroll
      for (int nt = 0; nt < 2; nt++) {
        int rb = qn * 128 + wni * 32 + nt * 16 + l15;
        bfr[qn][kk][nt] = *(const bf16x8*)&Bls[b][rb * 64 + (((kk * 4 + quad) ^ (rb & 7)) << 3)];
      }
  };
  auto mfma16 = [&](int qm, int qn) {
    __builtin_amdgcn_s_setprio(1);
#pragma unroll
    for (int kk = 0; kk < 2; kk++)
#pragma unroll
      for (int mt = 0; mt < 4; mt++)
#pragma unroll
        for (int nt = 0; nt < 2; nt++)
          acc[qm * 4 + mt][qn * 2 + nt] = __builtin_amdgcn_mfma_f32_16x16x32_bf16(
              af[kk][mt], bfr[qn][kk][nt], acc[qm * 4 + mt][qn * 2 + nt], 0, 0, 0);
    __builtin_amdgcn_s_setprio(0);
  };

  int nk = K >> 6;  // even
  stageA(0, 0, 0); stageB(0, 0, 0); stageB(0, 1, 0); stageA(0, 1, 0);
  stageA(1, 0, 1); stageB(1, 1, 1);
  VMCNT6();
  BARRIER();

  for (int t = 0; t < nk; t += 2) {
#pragma unroll
    for (int uu = 0; uu < 2; uu++) {
      const int tt = t + uu;
      const int cur = uu;
      // ph0: quadrant (0,0); read A0 + B0 (16 ds_reads)
      readA(cur, 0); readB(cur, 0);
      if (tt + 1 < nk) stageB(cur ^ 1, 0, tt + 1);
      BARRIER();
      mfma16(0, 0);
      BARRIER();
      // ph1: quadrant (0,1); read B1 (8 ds_reads; covered by prev ph3 vmcnt)
      readB(cur, 1);
      if (tt + 1 < nk) stageA(cur ^ 1, 1, tt + 1);
      VMCNT6();
      BARRIER();
      mfma16(0, 1);
      BARRIER();
      // ph2: quadrant (1,1); read A1 (8 ds_reads)
      readA(cur, 1);
      if (tt + 2 < nk) stageA(cur, 0, tt + 2);
      BARRIER();
      mfma16(1, 1);
      BARRIER();
      // ph3: quadrant (1,0); no reads (B0 fragments register-held from ph0)
      if (tt + 2 < nk) stageB(cur, 1, tt + 2);
      VMCNT6();
      BARRIER();
      mfma16(1, 0);
      BARRIER();
    }
  }

#pragma unroll
  for (int MT = 0; MT < 8; MT++) {
#pragma unroll
    for (int NT = 0; NT < 4; NT++) {
      int col = n0 + (NT >> 1) * 128 + wni * 32 + (NT & 1) * 16 + l15;
      float bv = bias[col];
#pragma unroll
      for (int r = 0; r < 4; r++) {
        int row = m0 + (MT >> 2) * 128 + wmi * 64 + (MT & 3) * 16 + quad * 4 + r;
        float v = acc[MT][NT][r] + bv;
        if (EPI == 1) v = 0.5f * v * (1.0f + erff(v * 0.7071067811865475f));
        ((bf16*)Cout)[(size_t)row * N + col] = (bf16)v;
      }
    }
  }
}

// ---------------------------------------------------------------------------
// GEMM 256x128 2-phase (QKV / attn-out / proj). R6-R8 verified.
// ---------------------------------------------------------------------------
template <int EPI>
__global__ __launch_bounds__(512)
void gemm256n_kernel(const bf16* __restrict__ A, const bf16* __restrict__ Bt,
                     const float* __restrict__ bias, const float* __restrict__ res,
                     void* __restrict__ Cout, int M, int N, int K) {
  __shared__ bf16 Als[2][256 * 64];
  __shared__ bf16 Bls[2][128 * 64];
  int tid = threadIdx.x;
  int wave = tid >> 6, lane = tid & 63;
  int l15 = lane & 15, quad = lane >> 4;
  int wmi = wave >> 2, wni = wave & 3;
  int m0 = blockIdx.y * 256, n0 = blockIdx.x * 128;

  int u0 = tid, u1 = tid + 512;
  int r0 = u0 >> 3, c0 = ((u0 & 7) ^ (r0 & 7)) << 3;
  int r1 = u1 >> 3, c1 = ((u1 & 7) ^ (r1 & 7)) << 3;
  const bf16* aB0 = A + (size_t)(m0 + r0) * K + c0;
  const bf16* aB1 = A + (size_t)(m0 + r1) * K + c1;
  const bf16* bB0 = Bt + (size_t)(n0 + r0) * K + c0;
  const bf16* bB1 = Bt + (size_t)(n0 + r1) * K + c1;
  int d0 = u0 * 8, d1 = u1 * 8;

  auto stageA = [&](int b, int h, int t) {
    size_t off = (size_t)h * 128 * K + (size_t)t * 64;
    async_copy16(aB0 + off, &Als[b][h * 8192 + d0]);
    async_copy16(aB1 + off, &Als[b][h * 8192 + d1]);
  };
  auto stageB = [&](int b, int t) {
    size_t off = (size_t)t * 64;
    async_copy16(bB0 + off, &Bls[b][d0]);
    async_copy16(bB1 + off, &Bls[b][d1]);
  };

  f32x4 acc[8][2] = {};
  bf16x8 af[2][4], bfr[2][2];

  auto readA = [&](int b, int qm) {
#pragma unroll
    for (int kk = 0; kk < 2; kk++)
#pragma unroll
      for (int mt = 0; mt < 4; mt++) {
        int ra = qm * 128 + wmi * 64 + mt * 16 + l15;
        af[kk][mt] = *(const bf16x8*)&Als[b][ra * 64 + (((kk * 4 + quad) ^ (ra & 7)) << 3)];
      }
  };
  auto readB = [&](int b) {
#pragma unroll
    for (int kk = 0; kk < 2; kk++)
#pragma unroll
      for (int nt = 0; nt < 2; nt++) {
        int rb = wni * 32 + nt * 16 + l15;
        bfr[kk][nt] = *(const bf16x8*)&Bls[b][rb * 64 + (((kk * 4 + quad) ^ (rb & 7)) << 3)];
      }
  };
  auto mfma16 = [&](int qm) {
    __builtin_amdgcn_s_setprio(1);
#pragma unroll
    for (int kk = 0; kk < 2; kk++)
#pragma unroll
      for (int mt = 0; mt < 4; mt++)
#pragma unroll
        for (int nt = 0; nt < 2; nt++)
          acc[qm * 4 + mt][nt] = __builtin_amdgcn_mfma_f32_16x16x32_bf16(
              af[kk][mt], bfr[kk][nt], acc[qm * 4 + mt][nt], 0, 0, 0);
    __builtin_amdgcn_s_setprio(0);
  };

  int nk = K >> 6;  // even
  stageB(0, 0); stageB(1, 1); stageA(0, 0, 0); stageA(0, 1, 0);
  VMCNT0();
  BARRIER();

  for (int t = 0; t < nk; t += 2) {
#pragma unroll
    for (int uu = 0; uu < 2; uu++) {
      const int tt = t + uu;
      const int cur = uu;
      // ph0
      readA(cur, 0); readB(cur);
      if (tt + 1 < nk) { stageA(cur ^ 1, 0, tt + 1); VMCNT4(); }
      else { VMCNT0(); }
      BARRIER();
      mfma16(0);
      BARRIER();
      // ph1
      readA(cur, 1);
      if (tt + 1 < nk) stageA(cur ^ 1, 1, tt + 1);
      if (tt + 2 < nk) { stageB(cur, tt + 2); VMCNT4(); }
      else { VMCNT2(); }
      BARRIER();
      mfma16(1);
      BARRIER();
    }
  }

#pragma unroll
  for (int MT = 0; MT < 8; MT++) {
#pragma unroll
    for (int NT = 0; NT < 2; NT++) {
      int col = n0 + wni * 32 + NT * 16 + l15;
      float bv = bias[col];
#pragma unroll
      for (int r = 0; r < 4; r++) {
        int row = m0 + (MT >> 2) * 128 + wmi * 64 + (MT & 3) * 16 + quad * 4 + r;
        float v = acc[MT][NT][r] + bv;
        if (EPI == 1) v = 0.5f * v * (1.0f + erff(v * 0.7071067811865475f));
        if (EPI == 2) {
          v += res[(size_t)row * N + col];
          ((float*)Cout)[(size_t)row * N + col] = v;
        } else {
          ((bf16*)Cout)[(size_t)row * N + col] = (bf16)v;
        }
      }
    }
  }
}

// ---------------------------------------------------------------------------
// pack_v: per (b,h,kt) V transposed into [d][chunk^swizzle], 16B chunks.
// ---------------------------------------------------------------------------
__global__ __launch_bounds__(256)
void pack_v_kernel(const bf16* __restrict__ qkv, bf16* __restrict__ Vpack) {
  __shared__ bf16 Vst[64][132];
  int kt = blockIdx.x, h = blockIdx.y, b = blockIdx.z;
  int tid = threadIdx.x;
  const size_t rs = 3 * DD;
  const bf16* vb = qkv + (size_t)b * LL * rs + (size_t)(kt * 64) * rs + 2 * DD + h * HSS;
  bf16* vp = Vpack + ((size_t)(b * NHH + h) * 16 + kt) * (128 * 64);
#pragma unroll
  for (int i = 0; i < 4; i++) {
    int u = i * 256 + tid;
    int kk = u >> 4, c = u & 15;
    *(bf16x8*)&Vst[kk][c * 8] = *(const bf16x8*)(vb + (size_t)kk * rs + c * 8);
  }
  __syncthreads();
#pragma unroll
  for (int i = 0; i < 4; i++) {
    int u = i * 256 + tid;
    int d = u >> 3, c = u & 7;
    bf16x8 t;
#pragma unroll
    for (int j = 0; j < 8; j++) t[j] = Vst[c * 8 + j][d];
    *(bf16x8*)(vp + d * 64 + ((c ^ (d & 7))) * 8) = t;
  }
}

// ---------------------------------------------------------------------------
// relband v4 + setprio (R6-R8 proven, ~45us, occupancy 36%).
// ---------------------------------------------------------------------------
__global__ __launch_bounds__(256)
void relband_kernel(const bf16* __restrict__ qkv, const bf16* __restrict__ ErP,
                    f16* __restrict__ band) {
  int tid = threadIdx.x, wave = tid >> 6, lane = tid & 63;
  int l15 = lane & 15, quad = lane >> 4;
  int h = blockIdx.y, b = blockIdx.z;
  const size_t rs = 3 * DD;
  const bf16* qbase = qkv + (size_t)b * LL * rs + h * HSS;
  f16* bbase = band + (size_t)(b * NHH + h) * (136 * 4096);

#pragma unroll 1
  for (int ph = 0; ph < 2; ph++) {
    int qb = ph ? 15 - blockIdx.x : blockIdx.x;
    int qw0 = qb * 64 + wave * 16;

    bf16x8 qf[4];
#pragma unroll
    for (int st = 0; st < 4; st++)
      qf[st] = *(const bf16x8*)(qbase + (size_t)(qw0 + l15) * rs + st * 32 + quad * 8);

#pragma unroll 1
    for (int kt = 0; kt <= qb; kt++) {
      int k0 = kt * 64;
      int kmax_off = qw0 + 15 - k0;
      int m_base = 1008 - qw0 + k0;
      int gb = m_base >> 4;
      int ntR = (kmax_off >> 4) + 1;
      if (ntR > 4) ntR = 4;

      f32x4 rr[5] = {};
      __builtin_amdgcn_s_setprio(1);
#pragma unroll
      for (int n = 0; n < 5; n++) {
        if (n <= ntR) {
          int g = gb + n;
          if (g > 63) g = 63;
          const bf16* ep = ErP + (size_t)g * 2048 + lane * 8;
#pragma unroll
          for (int st = 0; st < 4; st++) {
            bf16x8 ef = *(const bf16x8*)(ep + st * 512);
            rr[n] = __builtin_amdgcn_mfma_f32_16x16x32_bf16(qf[st], ef, rr[n], 0, 0, 0);
          }
        }
      }
      __builtin_amdgcn_s_setprio(0);

      f16x4 sf[4];
#pragma unroll
      for (int rg = 0; rg < 4; rg++) {
        int qloc = quad * 4 + rg;
        int tt = 15 - qloc + l15;
        int src = (lane & 48) | (tt & 15);
        float shv[5];
#pragma unroll
        for (int n = 0; n < 5; n++)
          shv[n] = (n <= ntR) ? __shfl(rr[n][rg], src) : 0.f;
#pragma unroll
        for (int nt = 0; nt < 4; nt++)
          sf[nt][rg] = (f16)((tt & 16) ? shv[nt + 1] : shv[nt]);
      }
      f16* tb = bbase + (size_t)TRI(qb, kt) * 4096;
#pragma unroll
      for (int nt = 0; nt < 4; nt++)
        if (nt * 16 <= kmax_off)
          *(f16x4*)(tb + (wave * 4 + nt) * 256 + l15 * 16 + quad * 4) = sf[nt];
    }
  }
}

// ---------------------------------------------------------------------------
// Flash attention v11: SINGLE-buffered K/V, ~42KB LDS -> 2-3 blocks/CU
// (R10/R11 design; passed R11). Two __syncthreads per k-tile. K staged
// direct from qkv via pre-swizzled global addresses; V from Vpack; band
// from relband. setprio + T13 defer-max kept.
// ---------------------------------------------------------------------------
__global__ __launch_bounds__(256)
void flash_kernel(const bf16* __restrict__ qkv, const bf16* __restrict__ Vpack,
                  const f16* __restrict__ band, bf16* __restrict__ y) {
  __shared__ bf16 Kls[64 * 128];   // 16 KB
  __shared__ bf16 Vls[128 * 64];   // 16 KB
  __shared__ bf16 Pls[4][16][72];  // 9 KB

  int tid = threadIdx.x, wave = tid >> 6, lane = tid & 63;
  int l15 = lane & 15, quad = lane >> 4;
  int h = blockIdx.y, b = blockIdx.z;

  const size_t rs = 3 * DD;
  const bf16* qbase = qkv + (size_t)b * LL * rs + h * HSS;
  const bf16* kb = qbase + DD;  // K head base
  const bf16* vp = Vpack + (size_t)(b * NHH + h) * 16 * (128 * 64);
  const f16* bnd = band + (size_t)(b * NHH + h) * (136 * 4096);

  // per-thread pre-swizzled K source offsets (tile-invariant part)
  size_t koff[4];
  int ldso[4];
#pragma unroll
  for (int i = 0; i < 4; i++) {
    int off = (wave * 4 + i) * 512 + lane * 8;
    int u = off >> 3;
    int kk = u >> 4, c = u & 15;
    koff[i] = (size_t)kk * rs + (size_t)(((c ^ kk) & 15) * 8);
    ldso[i] = off;
  }

#pragma unroll 1
  for (int ph = 0; ph < 2; ph++) {
    int qb = ph ? 15 - blockIdx.x : blockIdx.x;
    int qw0 = qb * 64 + wave * 16;
    int nkt = qb + 1;

    bf16x8 qf[4];
#pragma unroll
    for (int st = 0; st < 4; st++)
      qf[st] = *(const bf16x8*)(qbase + (size_t)(qw0 + l15) * rs + st * 32 + quad * 8);

    f32x4 o[8] = {};
    float mrow[4] = {-INFINITY, -INFINITY, -INFINITY, -INFINITY};
    float lrow[4] = {0.f, 0.f, 0.f, 0.f};

#pragma unroll 1
    for (int kt = 0; kt < nkt; kt++) {
      int k0 = kt * 64;
      int kmax_off = qw0 + 15 - k0;  // wave-uniform
      __syncthreads();  // previous tile's (and phase's) readers done

      // band fragment loads (VGPR; retire with the barrier drain below)
      const f16* tb = bnd + (size_t)TRI(qb, kt) * 4096;
      f16x4 srl[4] = {};
#pragma unroll
      for (int nt = 0; nt < 4; nt++)
        if (nt * 16 <= kmax_off)
          srl[nt] = *(const f16x4*)(tb + (wave * 4 + nt) * 256 + l15 * 16 + quad * 4);

      // stage THIS tile's K/V
      {
        const bf16* ks = kb + (size_t)kt * 64 * rs;
        const bf16* vs = vp + (size_t)kt * (128 * 64);
#pragma unroll
        for (int i = 0; i < 4; i++) {
          async_copy16(ks + koff[i], &Kls[ldso[i]]);
          async_copy16(vs + ldso[i], &Vls[ldso[i]]);
        }
      }
      __syncthreads();  // drain: K/V resident, srl ready

      // S = Q K^T
      f32x4 sa[4] = {};
      __builtin_amdgcn_s_setprio(1);
#pragma unroll
      for (int nt = 0; nt < 4; nt++) {
        if (nt * 16 <= kmax_off) {
          int kk = nt * 16 + l15;
#pragma unroll
          for (int st = 0; st < 4; st++) {
            bf16x8 kf = *(const bf16x8*)&Kls[kk * 128 + (((st * 4 + quad) ^ l15) & 15) * 8];
            sa[nt] = __builtin_amdgcn_mfma_f32_16x16x32_bf16(qf[st], kf, sa[nt], 0, 0, 0);
          }
        }
      }
      __builtin_amdgcn_s_setprio(0);

      // combine + mask + row max
      float pmx[4] = {-INFINITY, -INFINITY, -INFINITY, -INFINITY};
#pragma unroll
      for (int nt = 0; nt < 4; nt++) {
        if (nt * 16 <= kmax_off) {
          int kg = k0 + nt * 16 + l15;
#pragma unroll
          for (int rg = 0; rg < 4; rg++) {
            int qg = qw0 + quad * 4 + rg;
            float v = (sa[nt][rg] + (float)srl[nt][rg]) * SCALE;
            v = (kg <= qg) ? v : -INFINITY;
            sa[nt][rg] = v;
            pmx[rg] = fmaxf(pmx[rg], v);
          }
        } else {
#pragma unroll
          for (int rg = 0; rg < 4; rg++) sa[nt][rg] = -INFINITY;
        }
      }

      // online softmax with defer-max (T13)
      float vmx[4];
      bool need = false;
#pragma unroll
      for (int rg = 0; rg < 4; rg++) {
        float v = pmx[rg];
        v = fmaxf(v, __shfl_xor(v, 1));
        v = fmaxf(v, __shfl_xor(v, 2));
        v = fmaxf(v, __shfl_xor(v, 4));
        v = fmaxf(v, __shfl_xor(v, 8));
        vmx[rg] = v;
        need = need || (v - mrow[rg] > 8.0f);
      }
      if (__any(need)) {
#pragma unroll
        for (int rg = 0; rg < 4; rg++) {
          float mnew = fmaxf(mrow[rg], vmx[rg]);
          float alpha = __expf(mrow[rg] - mnew);
          mrow[rg] = mnew;
          lrow[rg] *= alpha;
#pragma unroll
          for (int nt = 0; nt < 8; nt++) o[nt][rg] *= alpha;
        }
      }

      float ls[4] = {0.f, 0.f, 0.f, 0.f};
#pragma unroll
      for (int nt = 0; nt < 4; nt++)
#pragma unroll
        for (int rg = 0; rg < 4; rg++) {
          float p = __expf(sa[nt][rg] - mrow[rg]);
          ls[rg] += p;
          Pls[wave][quad * 4 + rg][nt * 16 + l15] = (bf16)p;
        }
#pragma unroll
      for (int rg = 0; rg < 4; rg++) {
        float v = ls[rg];
        v += __shfl_xor(v, 1);
        v += __shfl_xor(v, 2);
        v += __shfl_xor(v, 4);
        v += __shfl_xor(v, 8);
        lrow[rg] += v;
      }
      // Pls is per-wave: same-wave DS ordering suffices, no barrier

      // O += P @ V
      bf16x8 pf[2];
#pragma unroll
      for (int s2 = 0; s2 < 2; s2++)
        pf[s2] = *(const bf16x8*)&Pls[wave][l15][s2 * 32 + quad * 8];
      __builtin_amdgcn_s_setprio(1);
#pragma unroll
      for (int nt = 0; nt < 8; nt++) {
        int d = nt * 16 + l15;
#pragma unroll
        for (int s2 = 0; s2 < 2; s2++) {
          if (s2 * 32 <= kmax_off) {
            bf16x8 vf = *(const bf16x8*)&Vls[d * 64 + (((s2 * 4 + quad) ^ (l15 & 7)) & 7) * 8];
            o[nt] = __builtin_amdgcn_mfma_f32_16x16x32_bf16(pf[s2], vf, o[nt], 0, 0, 0);
          }
        }
      }
      __builtin_amdgcn_s_setprio(0);
    }

    // finalize phase: O / l -> y[b, q, h*128 + d] bf16
#pragma unroll
    for (int rg = 0; rg < 4; rg++) {
      float inv = 1.0f / lrow[rg];
      int qg = qw0 + quad * 4 + rg;
      bf16* yr = y + ((size_t)b * LL + qg) * DD + h * HSS;
#pragma unroll
      for (int nt = 0; nt < 8; nt++) yr[nt * 16 + l15] = (bf16)(o[nt][rg] * inv);
    }
  }
}

// ---------------------------------------------------------------------------
extern "C" void kernel_launch(void* const* d_in, const int* in_sizes, int n_in,
                              void* d_out, int out_size, void* d_ws, size_t ws_size,
                              hipStream_t stream) {
  const float* x = (const float*)d_in[0];
  const float* W_qkv = (const float*)d_in[1];
  const float* b_qkv = (const float*)d_in[2];
  const float* W_o = (const float*)d_in[3];
  const float* b_o = (const float*)d_in[4];
  const float* Er = (const float*)d_in[5];
  const float* ln1_g = (const float*)d_in[6];
  const float* ln1_b = (const float*)d_in[7];
  const float* ln2_g = (const float*)d_in[8];
  const float* ln2_b = (const float*)d_in[9];
  const float* W_fc = (const float*)d_in[10];
  const float* b_fc = (const float*)d_in[11];
  const float* W_proj = (const float*)d_in[12];
  const float* b_proj = (const float*)d_in[13];
  float* out = (float*)d_out;

  char* p = (char*)d_ws;
  auto alloc = [&](size_t bytes) {
    char* r = p;
    p += (bytes + 255) & ~(size_t)255;
    return r;
  };
  bf16* Wt_qkv = (bf16*)alloc((size_t)3072 * 1024 * 2);
  bf16* Wt_o   = (bf16*)alloc((size_t)1024 * 1024 * 2);
  bf16* Wt_fc  = (bf16*)alloc((size_t)4096 * 1024 * 2);
  bf16* Wt_pr  = (bf16*)alloc((size_t)1024 * 4096 * 2);
  bf16* ErP    = (bf16*)alloc((size_t)1024 * 128 * 2);
  bf16* xn     = (bf16*)alloc((size_t)8192 * 1024 * 2);
  bf16* qkvb   = (bf16*)alloc((size_t)8192 * 3072 * 2);  // + yb = hb region
  bf16* yb     = (bf16*)alloc((size_t)8192 * 1024 * 2);  // must follow qkvb
  bf16* Vpack  = (bf16*)alloc((size_t)64 * 16 * 128 * 64 * 2);
  f16*  band   = (f16*)alloc((size_t)64 * 136 * 4096 * 2);  // 71.3 MB
  float* x2    = (float*)band;  // alias: band dead before x2 is written
  bf16* hb     = qkvb;          // spans qkvb+yb (66MB >= 64MB needed)

  // weight prep (single launch)
  prep_kernel<<<12352, 256, 0, stream>>>(W_qkv, W_o, W_fc, W_proj, Er,
                                         Wt_qkv, Wt_o, Wt_fc, Wt_pr, ErP);

  // block
  ln_kernel<<<8192, 256, 0, stream>>>(x, ln1_g, ln1_b, xn);
  gemm256n_kernel<0><<<dim3(24, 32), 512, 0, stream>>>(xn, Wt_qkv, b_qkv, nullptr, qkvb, 8192, 3072, 1024);
  pack_v_kernel<<<dim3(16, 8, 8), 256, 0, stream>>>(qkvb, Vpack);
  relband_kernel<<<dim3(8, 8, 8), 256, 0, stream>>>(qkvb, ErP, band);
  flash_kernel<<<dim3(8, 8, 8), 256, 0, stream>>>(qkvb, Vpack, band, yb);
  gemm256n_kernel<2><<<dim3(8, 32), 512, 0, stream>>>(yb, Wt_o, b_o, x, x2, 8192, 1024, 1024);
  ln_kernel<<<8192, 256, 0, stream>>>(x2, ln2_g, ln2_b, xn);
  gemm256_kernel<1><<<dim3(16, 32), 512, 0, stream>>>(xn, Wt_fc, b_fc, hb, 8192, 4096, 1024);
  gemm256n_kernel<2><<<dim3(8, 32), 512, 0, stream>>>(hb, Wt_pr, b_proj, x2, out, 8192, 1024, 4096);
}